// Round 6
// baseline (579.932 us; speedup 1.0000x reference)
//
#include <hip/hip_runtime.h>
#include <hip/hip_bf16.h>

typedef __bf16 bf16;
typedef unsigned short u16;
typedef bf16 bf16x8 __attribute__((ext_vector_type(8)));
typedef bf16 bf16x2 __attribute__((ext_vector_type(2)));
typedef u16  u16x8  __attribute__((ext_vector_type(8)));
typedef u16  u16x4  __attribute__((ext_vector_type(4)));
typedef float f32x4 __attribute__((ext_vector_type(4)));

#define MFMA16(a,b,c) __builtin_amdgcn_mfma_f32_16x16x32_bf16((a),(b),(c),0,0,0)
#define QSCALE 0.09016844005625f   // (1/16) * log2(e)
#define NITEMS 3584                // 28 segs * 128 q-strips

__device__ inline unsigned pack2(float a, float b) {
    bf16x2 t; t[0] = (bf16)a; t[1] = (bf16)b;
    return __builtin_bit_cast(unsigned, t);
}

// W (f32 [c][d]) -> bf16 transposed [which][d][c]
__global__ void cvt_w(const float* __restrict__ Wq, const float* __restrict__ Wk,
                      const float* __restrict__ Wv, bf16* __restrict__ Wbt) {
    int idx = blockIdx.x * 256 + threadIdx.x;
    int which = idx >> 16;
    int rem = idx & 65535;
    int c = rem >> 8, d = rem & 255;
    const float* W = (which == 0) ? Wq : (which == 1) ? Wk : Wv;
    Wbt[(size_t)which * 65536 + d * 256 + c] = (bf16)W[c * 256 + d];
}

// ---------------------------------------------------------------- QKV GEMM
// block = 64 tokens x full 256 d (nt looped inside; x converted once).
__global__ __launch_bounds__(256, 2)
void qkv_gemm(const float* __restrict__ x, const bf16* __restrict__ Wbt,
              bf16* __restrict__ Qb, bf16* __restrict__ Kb,
              bf16* __restrict__ Vtt1, bf16* __restrict__ Vtt2, bf16* __restrict__ Vtt4) {
    __shared__ __align__(16) u16 lA[64 * 136];
    __shared__ __align__(16) u16 lB[64 * 136];
    int mt = blockIdx.x, which = blockIdx.y;
    int tid = threadIdx.x, wv = tid >> 6, lane = tid & 63;
    int l15 = lane & 15, quad = lane >> 4;

    f32x4 acc[4][4] = {};
    const float* Ax = x + (size_t)(mt * 64) * 256;
    const bf16* Bw = Wbt + (size_t)which * 65536;
    int row = tid >> 2, c0 = (tid & 3) * 32;

    for (int kh = 0; kh < 2; kh++) {
        __syncthreads();
        #pragma unroll
        for (int i = 0; i < 4; i++) {
            float4 f0 = *(const float4*)(Ax + row * 256 + kh * 128 + c0 + i * 8);
            float4 f1 = *(const float4*)(Ax + row * 256 + kh * 128 + c0 + i * 8 + 4);
            bf16x8 v;
            v[0] = (bf16)f0.x; v[1] = (bf16)f0.y; v[2] = (bf16)f0.z; v[3] = (bf16)f0.w;
            v[4] = (bf16)f1.x; v[5] = (bf16)f1.y; v[6] = (bf16)f1.z; v[7] = (bf16)f1.w;
            *(bf16x8*)((bf16*)lA + row * 136 + c0 + i * 8) = v;
        }
        for (int nt = 0; nt < 4; nt++) {
            __syncthreads();
            #pragma unroll
            for (int i = 0; i < 4; i++)
                *(bf16x8*)((bf16*)lB + row * 136 + c0 + i * 8) =
                    *(const bf16x8*)(Bw + (size_t)(nt * 64 + row) * 256 + kh * 128 + c0 + i * 8);
            __syncthreads();
            #pragma unroll
            for (int ks = 0; ks < 4; ks++) {
                bf16x8 a = *(const bf16x8*)((bf16*)lA + (wv * 16 + l15) * 136 + ks * 32 + quad * 8);
                #pragma unroll
                for (int ns = 0; ns < 4; ns++) {
                    bf16x8 b2 = *(const bf16x8*)((bf16*)lB + (ns * 16 + l15) * 136 + ks * 32 + quad * 8);
                    acc[nt][ns] = MFMA16(a, b2, acc[nt][ns]);
                }
            }
        }
    }

    // Epilogue per nt, staged through LDS for coalesced stores.
    u16* lT = lA;                     // [64][72] u16
    float sc = (which == 0) ? QSCALE : 1.0f;
    for (int nt = 0; nt < 4; nt++) {
        __syncthreads();
        if (which < 2) {
            // layout [tok][col]
            #pragma unroll
            for (int ns = 0; ns < 4; ns++)
                #pragma unroll
                for (int r = 0; r < 4; r++) {
                    bf16 v = (bf16)(acc[nt][ns][r] * sc);
                    lT[(wv * 16 + quad * 4 + r) * 72 + ns * 16 + l15] = *(u16*)&v;
                }
            __syncthreads();
            bf16* outp = (which == 0) ? Qb : Kb;
            int tokl = tid >> 2, ch = tid & 3;
            u16x8 v0 = *(u16x8*)(lT + tokl * 72 + ch * 16);
            u16x8 v1 = *(u16x8*)(lT + tokl * 72 + ch * 16 + 8);
            u16* dst = (u16*)outp + (size_t)(mt * 64 + tokl) * 256 + nt * 64 + ch * 16;
            *(u16x8*)dst = v0;
            *(u16x8*)(dst + 8) = v1;
        } else {
            // layout [col d][tok]
            #pragma unroll
            for (int ns = 0; ns < 4; ns++)
                #pragma unroll
                for (int r = 0; r < 4; r++) {
                    bf16 v = (bf16)acc[nt][ns][r];
                    lT[(ns * 16 + l15) * 72 + wv * 16 + quad * 4 + r] = *(u16*)&v;
                }
            __syncthreads();
            int gtok = mt * 64;
            int bL = gtok >> 13, n0 = gtok & 8191;
            int d_l = tid >> 2, q = tid & 3;
            int dg = nt * 64 + d_l;
            {   // cfg1
                int s1 = n0 >> 11, j1 = n0 & 2047;
                u16* dst = (u16*)Vtt1 + ((size_t)(bL * 4 + s1) * 64 + (j1 >> 5) + (q >> 1)) * 8192
                           + (size_t)dg * 32 + (q & 1) * 16;
                u16x8 a0 = *(u16x8*)(lT + d_l * 72 + q * 16);
                u16x8 a1 = *(u16x8*)(lT + d_l * 72 + q * 16 + 8);
                *(u16x8*)dst = a0; *(u16x8*)(dst + 8) = a1;
            }
            {   // cfg2: even tokens
                int s2 = n0 >> 12, j2 = (n0 & 4095) >> 1;
                u16x8 e;
                #pragma unroll
                for (int i = 0; i < 8; i++) e[i] = lT[d_l * 72 + q * 16 + 2 * i];
                u16* dst = (u16*)Vtt2 + ((size_t)(bL * 2 + s2) * 64 + (j2 >> 5)) * 8192
                           + (size_t)dg * 32 + q * 8;
                *(u16x8*)dst = e;
            }
            {   // cfg4: tokens %4==0
                int j4 = n0 >> 2;
                u16x4 e;
                #pragma unroll
                for (int i = 0; i < 4; i++) e[i] = lT[d_l * 72 + q * 16 + 4 * i];
                u16* dst = (u16*)Vtt4 + ((size_t)bL * 64 + (j4 >> 5)) * 8192
                           + (size_t)dg * 32 + (j4 & 31) + q * 4;
                *(u16x4*)dst = e;
            }
        }
    }
}

// ---------------------------------------------------------------- attention
// Persistent waves; one item = one 16-q strip of one segment. NO LDS, NO
// barriers: K/V MFMA fragments loaded directly from global (L2-served).
__global__ __launch_bounds__(256, 3)
void attn(const bf16* __restrict__ Qb, const bf16* __restrict__ Kb,
          const bf16* __restrict__ Vtt1, const bf16* __restrict__ Vtt2,
          const bf16* __restrict__ Vtt4,
          float* __restrict__ O1, float* __restrict__ O2, float* __restrict__ O4,
          float* __restrict__ D1, float* __restrict__ D2, float* __restrict__ D4,
          int* __restrict__ qcount) {
    const int lane = threadIdx.x & 63;
    const int l15 = lane & 15, quad = lane >> 4;

    for (;;) {
        int item;
        if (lane == 0) item = atomicAdd(qcount, 1);
        item = __shfl(item, 0, 64);
        if (item >= NITEMS) return;

        const int s = 127 - (item / 28);      // heavy strips first
        const int seg = item % 28;
        int lr, b, sg;
        if (seg < 16)      { lr = 0; sg = seg >> 2;        b = seg & 3;        }
        else if (seg < 24) { lr = 1; sg = (seg - 16) >> 2; b = (seg - 16) & 3; }
        else               { lr = 2; sg = 0;               b = seg - 24;       }
        const int rr = 1 << lr;
        const size_t base = (size_t)b * 8192 + (size_t)sg * (2048 << lr);
        const size_t pbase = (size_t)b * (8192 >> lr) + (size_t)sg * 2048;
        const int segi = (lr == 0) ? (b * 4 + sg) : (lr == 1) ? (b * 2 + sg) : b;
        const bf16* Vtt = (lr == 0) ? Vtt1 : (lr == 1) ? Vtt2 : Vtt4;
        float* Op = (lr == 0) ? O1 : (lr == 1) ? O2 : O4;
        float* Dp = (lr == 0) ? D1 : (lr == 1) ? D2 : D4;

        const int qi = s * 16 + l15;
        const bf16* qp = Qb + (base + (size_t)qi * rr) * 256 + quad * 8;
        bf16x8 qf[8];
        #pragma unroll
        for (int ks = 0; ks < 8; ks++) qf[ks] = *(const bf16x8*)(qp + ks * 32);

        const bf16* Kl = Kb + (base + (size_t)l15 * rr) * 256 + quad * 8;
        const bf16* Vl = Vtt + (size_t)segi * 524288 + l15 * 32 + quad * 8;

        f32x4 o[16] = {};
        float m_run = -1e30f, l_run = 0.f;

        const int nkt = (s >> 1) + 1;
        for (int kt = 0; kt < nkt; kt++) {
            // S^T = K Q^T : A = K rows (m=key), direct from global
            f32x4 sf[2] = {};
            #pragma unroll
            for (int ks = 0; ks < 8; ks++) {
                #pragma unroll
                for (int kb = 0; kb < 2; kb++) {
                    bf16x8 kf = *(const bf16x8*)(Kl + (size_t)((kt * 32 + kb * 16) * rr) * 256 + ks * 32);
                    sf[kb] = MFMA16(kf, qf[ks], sf[kb]);
                }
            }
            // causal mask (diagonal tile only); running max
            float mx = -1e30f;
            #pragma unroll
            for (int kb = 0; kb < 2; kb++)
                #pragma unroll
                for (int r = 0; r < 4; r++) {
                    float v = sf[kb][r];
                    if (kt == nkt - 1) {
                        int key = kt * 32 + kb * 16 + quad * 4 + r;
                        if (key > qi) v = -1e30f;
                    }
                    sf[kb][r] = v;
                    mx = fmaxf(mx, v);
                }
            mx = fmaxf(mx, __shfl_xor(mx, 16));
            mx = fmaxf(mx, __shfl_xor(mx, 32));
            float mold = m_run;
            float mnew = fmaxf(mold, mx);
            m_run = mnew;
            float a = exp2f(mold - mnew);
            float rs = 0.f;
            #pragma unroll
            for (int kb = 0; kb < 2; kb++)
                #pragma unroll
                for (int r = 0; r < 4; r++) {
                    float e = exp2f(sf[kb][r] - mnew);
                    sf[kb][r] = e;
                    rs += e;
                }
            rs += __shfl_xor(rs, 16);
            rs += __shfl_xor(rs, 32);
            l_run = l_run * a + rs;
            if (__any(mnew > mold)) {
                #pragma unroll
                for (int f = 0; f < 16; f++)
                    #pragma unroll
                    for (int r = 0; r < 4; r++) o[f][r] *= a;
            }
            // P^T B-fragment: pack bf16 pairs, 8 u32 cross-quad shuffles
            unsigned pk00 = pack2(sf[0][0], sf[0][1]);
            unsigned pk01 = pack2(sf[0][2], sf[0][3]);
            unsigned pk10 = pack2(sf[1][0], sf[1][1]);
            unsigned pk11 = pack2(sf[1][2], sf[1][3]);
            int src0 = l15 + 16 * ((quad & 1) * 2);
            int src1 = src0 + 16;
            unsigned b00 = (unsigned)__shfl((int)pk00, src0, 64);
            unsigned b01 = (unsigned)__shfl((int)pk01, src0, 64);
            unsigned b02 = (unsigned)__shfl((int)pk00, src1, 64);
            unsigned b03 = (unsigned)__shfl((int)pk01, src1, 64);
            unsigned b10 = (unsigned)__shfl((int)pk10, src0, 64);
            unsigned b11 = (unsigned)__shfl((int)pk11, src0, 64);
            unsigned b12 = (unsigned)__shfl((int)pk10, src1, 64);
            unsigned b13 = (unsigned)__shfl((int)pk11, src1, 64);
            bool hi = (quad >> 1) != 0;
            union { bf16x8 v; unsigned u[4]; } pbu;
            pbu.u[0] = hi ? b10 : b00;
            pbu.u[1] = hi ? b11 : b01;
            pbu.u[2] = hi ? b12 : b02;
            pbu.u[3] = hi ? b13 : b03;
            // O^T += V^T P^T : A = V^T rows (m=d), contiguous 1KB/inst from Vtt
            const bf16* vt = Vl + (size_t)kt * 8192;
            #pragma unroll
            for (int f = 0; f < 16; f++) {
                bf16x8 vf = *(const bf16x8*)(vt + f * 512);
                o[f] = MFMA16(vf, pbu.v, o[f]);
            }
        }

        // epilogue: collision-free store of normalized partial + denom
        float invl = 1.0f / l_run;
        size_t pos = pbase + (size_t)qi;
        if (quad == 0) Dp[pos] = l_run * exp2f(m_run);
        float* orow = Op + pos * 256 + quad * 4;
        #pragma unroll
        for (int f = 0; f < 16; f++) {
            f32x4 v;
            #pragma unroll
            for (int r = 0; r < 4; r++) v[r] = o[f][r] * invl;
            *(f32x4*)(orow + f * 16) = v;
        }
    }
}

// ---------------------------------------------------------------- finalize
// out = (O1*d1 + O2*d2 + O4*d4) / (d1+d2+d4); O1 lives in d_out already.
__global__ void finalize(float* __restrict__ out, const float* __restrict__ O2,
                         const float* __restrict__ O4,
                         const float* __restrict__ D1, const float* __restrict__ D2,
                         const float* __restrict__ D4) {
    int g = blockIdx.x * 256 + threadIdx.x;     // 32768 tokens * 64 chunks
    int t = g >> 6, dc = (g & 63) * 4;
    int b = t >> 13, n = t & 8191;
    float d1 = D1[t];
    float4 o1 = *(float4*)(out + (size_t)t * 256 + dc);
    float ax = o1.x * d1, ay = o1.y * d1, az = o1.z * d1, aw = o1.w * d1;
    float den = d1;
    if ((n & 1) == 0) {
        int pos2 = b * 4096 + (n >> 12) * 2048 + ((n & 4095) >> 1);
        float d2 = D2[pos2];
        const float4 o2 = *(const float4*)(O2 + (size_t)pos2 * 256 + dc);
        ax += o2.x * d2; ay += o2.y * d2; az += o2.z * d2; aw += o2.w * d2;
        den += d2;
    }
    if ((n & 3) == 0) {
        int pos4 = b * 2048 + (n >> 2);
        float d4 = D4[pos4];
        const float4 o4 = *(const float4*)(O4 + (size_t)pos4 * 256 + dc);
        ax += o4.x * d4; ay += o4.y * d4; az += o4.z * d4; aw += o4.w * d4;
        den += d4;
    }
    float inv = 1.0f / den;
    float4 r; r.x = ax * inv; r.y = ay * inv; r.z = az * inv; r.w = aw * inv;
    *(float4*)(out + (size_t)t * 256 + dc) = r;
}

// ---------------------------------------------------------------- launch
extern "C" void kernel_launch(void* const* d_in, const int* in_sizes, int n_in,
                              void* d_out, int out_size, void* d_ws, size_t ws_size,
                              hipStream_t stream) {
    const float* x  = (const float*)d_in[0];
    const float* Wq = (const float*)d_in[1];
    const float* Wk = (const float*)d_in[2];
    const float* Wv = (const float*)d_in[3];
    float* out = (float*)d_out;

    char* ws = (char*)d_ws;
    bf16* Qb   = (bf16*)(ws);                        // 16 MB
    bf16* Kb   = (bf16*)(ws + 16777216);             // 16 MB
    bf16* Vtt1 = (bf16*)(ws + 33554432);             // 16 MB  [16 seg][64 kt][256][32]
    bf16* Vtt2 = (bf16*)(ws + 50331648);             //  8 MB
    bf16* Vtt4 = (bf16*)(ws + 58720256);             //  4 MB
    bf16* Wbt  = (bf16*)(ws + 62914560);             // 384 KB
    float* O2  = (float*)(ws + 63307776);            // 16 MB
    float* O4  = (float*)(ws + 80084992);            //  8 MB
    float* D1  = (float*)(ws + 88473600);            // 128 KB
    float* D2  = (float*)(ws + 88604672);            //  64 KB
    float* D4  = (float*)(ws + 88670208);            //  32 KB
    int* qcount = (int*)(ws + 88702976);             //   4 B

    hipMemsetAsync(qcount, 0, 4, stream);
    cvt_w<<<768, 256, 0, stream>>>(Wq, Wk, Wv, Wbt);
    qkv_gemm<<<dim3(512, 3), 256, 0, stream>>>(x, Wbt, Qb, Kb, Vtt1, Vtt2, Vtt4);
    attn<<<768, 256, 0, stream>>>(Qb, Kb, Vtt1, Vtt2, Vtt4, out, O2, O4, D1, D2, D4, qcount);
    finalize<<<8192, 256, 0, stream>>>(out, O2, O4, D1, D2, D4);
}

// Round 7
// 265.907 us; speedup vs baseline: 2.1810x; 2.1810x over previous
//
#include <hip/hip_runtime.h>
#include <hip/hip_bf16.h>

typedef __bf16 bf16;
typedef unsigned short u16;
typedef bf16 bf16x8 __attribute__((ext_vector_type(8)));
typedef bf16 bf16x2 __attribute__((ext_vector_type(2)));
typedef u16  u16x8  __attribute__((ext_vector_type(8)));
typedef u16  u16x4  __attribute__((ext_vector_type(4)));
typedef float f32x4 __attribute__((ext_vector_type(4)));

#define MFMA16(a,b,c) __builtin_amdgcn_mfma_f32_16x16x32_bf16((a),(b),(c),0,0,0)
#define QSCALE 0.09016844005625f   // (1/16) * log2(e)

__device__ inline unsigned pack2(float a, float b) {
    bf16x2 t; t[0] = (bf16)a; t[1] = (bf16)b;
    return __builtin_bit_cast(unsigned, t);
}

// W (f32 [c][d]) -> bf16 transposed [which][d][c]
__global__ void cvt_w(const float* __restrict__ Wq, const float* __restrict__ Wk,
                      const float* __restrict__ Wv, bf16* __restrict__ Wbt) {
    int idx = blockIdx.x * 256 + threadIdx.x;
    int which = idx >> 16;
    int rem = idx & 65535;
    int c = rem >> 8, d = rem & 255;
    const float* W = (which == 0) ? Wq : (which == 1) ? Wk : Wv;
    Wbt[(size_t)which * 65536 + d * 256 + c] = (bf16)W[c * 256 + d];
}

// ---------------------------------------------------------------- QKV GEMM
// block = 64 tokens x full 256 d (nt looped inside; x converted once).
__global__ __launch_bounds__(256, 2)
void qkv_gemm(const float* __restrict__ x, const bf16* __restrict__ Wbt,
              bf16* __restrict__ Qb, bf16* __restrict__ Kb,
              bf16* __restrict__ Vtt1, bf16* __restrict__ Vtt2, bf16* __restrict__ Vtt4) {
    __shared__ __align__(16) u16 lA[64 * 136];
    __shared__ __align__(16) u16 lB[64 * 136];
    int mt = blockIdx.x, which = blockIdx.y;
    int tid = threadIdx.x, wv = tid >> 6, lane = tid & 63;
    int l15 = lane & 15, quad = lane >> 4;

    f32x4 acc[4][4] = {};
    const float* Ax = x + (size_t)(mt * 64) * 256;
    const bf16* Bw = Wbt + (size_t)which * 65536;
    int row = tid >> 2, c0 = (tid & 3) * 32;

    for (int kh = 0; kh < 2; kh++) {
        __syncthreads();
        #pragma unroll
        for (int i = 0; i < 4; i++) {
            float4 f0 = *(const float4*)(Ax + row * 256 + kh * 128 + c0 + i * 8);
            float4 f1 = *(const float4*)(Ax + row * 256 + kh * 128 + c0 + i * 8 + 4);
            bf16x8 v;
            v[0] = (bf16)f0.x; v[1] = (bf16)f0.y; v[2] = (bf16)f0.z; v[3] = (bf16)f0.w;
            v[4] = (bf16)f1.x; v[5] = (bf16)f1.y; v[6] = (bf16)f1.z; v[7] = (bf16)f1.w;
            *(bf16x8*)((bf16*)lA + row * 136 + c0 + i * 8) = v;
        }
        for (int nt = 0; nt < 4; nt++) {
            __syncthreads();
            #pragma unroll
            for (int i = 0; i < 4; i++)
                *(bf16x8*)((bf16*)lB + row * 136 + c0 + i * 8) =
                    *(const bf16x8*)(Bw + (size_t)(nt * 64 + row) * 256 + kh * 128 + c0 + i * 8);
            __syncthreads();
            #pragma unroll
            for (int ks = 0; ks < 4; ks++) {
                bf16x8 a = *(const bf16x8*)((bf16*)lA + (wv * 16 + l15) * 136 + ks * 32 + quad * 8);
                #pragma unroll
                for (int ns = 0; ns < 4; ns++) {
                    bf16x8 b2 = *(const bf16x8*)((bf16*)lB + (ns * 16 + l15) * 136 + ks * 32 + quad * 8);
                    acc[nt][ns] = MFMA16(a, b2, acc[nt][ns]);
                }
            }
        }
    }

    // Epilogue per nt, staged through LDS for coalesced stores.
    u16* lT = lA;                     // [64][72] u16
    float sc = (which == 0) ? QSCALE : 1.0f;
    for (int nt = 0; nt < 4; nt++) {
        __syncthreads();
        if (which < 2) {
            // layout [tok][col]
            #pragma unroll
            for (int ns = 0; ns < 4; ns++)
                #pragma unroll
                for (int r = 0; r < 4; r++) {
                    bf16 v = (bf16)(acc[nt][ns][r] * sc);
                    lT[(wv * 16 + quad * 4 + r) * 72 + ns * 16 + l15] = *(u16*)&v;
                }
            __syncthreads();
            bf16* outp = (which == 0) ? Qb : Kb;
            int tokl = tid >> 2, ch = tid & 3;
            u16x8 v0 = *(u16x8*)(lT + tokl * 72 + ch * 16);
            u16x8 v1 = *(u16x8*)(lT + tokl * 72 + ch * 16 + 8);
            u16* dst = (u16*)outp + (size_t)(mt * 64 + tokl) * 256 + nt * 64 + ch * 16;
            *(u16x8*)dst = v0;
            *(u16x8*)(dst + 8) = v1;
        } else {
            // layout [col d][tok]
            #pragma unroll
            for (int ns = 0; ns < 4; ns++)
                #pragma unroll
                for (int r = 0; r < 4; r++) {
                    bf16 v = (bf16)acc[nt][ns][r];
                    lT[(ns * 16 + l15) * 72 + wv * 16 + quad * 4 + r] = *(u16*)&v;
                }
            __syncthreads();
            int gtok = mt * 64;
            int bL = gtok >> 13, n0 = gtok & 8191;
            int d_l = tid >> 2, q = tid & 3;
            int dg = nt * 64 + d_l;
            {   // cfg1
                int s1 = n0 >> 11, j1 = n0 & 2047;
                u16* dst = (u16*)Vtt1 + ((size_t)(bL * 4 + s1) * 64 + (j1 >> 5) + (q >> 1)) * 8192
                           + (size_t)dg * 32 + (q & 1) * 16;
                u16x8 a0 = *(u16x8*)(lT + d_l * 72 + q * 16);
                u16x8 a1 = *(u16x8*)(lT + d_l * 72 + q * 16 + 8);
                *(u16x8*)dst = a0; *(u16x8*)(dst + 8) = a1;
            }
            {   // cfg2: even tokens
                int s2 = n0 >> 12, j2 = (n0 & 4095) >> 1;
                u16x8 e;
                #pragma unroll
                for (int i = 0; i < 8; i++) e[i] = lT[d_l * 72 + q * 16 + 2 * i];
                u16* dst = (u16*)Vtt2 + ((size_t)(bL * 2 + s2) * 64 + (j2 >> 5)) * 8192
                           + (size_t)dg * 32 + q * 8;
                *(u16x8*)dst = e;
            }
            {   // cfg4: tokens %4==0
                int j4 = n0 >> 2;
                u16x4 e;
                #pragma unroll
                for (int i = 0; i < 4; i++) e[i] = lT[d_l * 72 + q * 16 + 4 * i];
                u16* dst = (u16*)Vtt4 + ((size_t)bL * 64 + (j4 >> 5)) * 8192
                           + (size_t)dg * 32 + (j4 & 31) + q * 4;
                *(u16x4*)dst = e;
            }
        }
    }
}

// ---------------------------------------------------------------- attention
// One block = 64 q-rows of one (seg, qt). Double-buffered LDS K/V tiles,
// 1 barrier per 32-key tile, conflict-free LDS strides, no atomics.
__global__ __launch_bounds__(256, 2)
void attn(const bf16* __restrict__ Qb, const bf16* __restrict__ Kb,
          const bf16* __restrict__ Vtt1, const bf16* __restrict__ Vtt2,
          const bf16* __restrict__ Vtt4,
          float* __restrict__ O1, float* __restrict__ O2, float* __restrict__ O4,
          float* __restrict__ D1, float* __restrict__ D2, float* __restrict__ D4) {
    __shared__ __align__(16) u16 K_l[2][32 * 264];   // 2 x 16896 B
    __shared__ __align__(16) u16 V_l[2][256 * 40];   // 2 x 20480 B (stride 20 banks)

    const int item = (int)blockIdx.x;
    const int qt = 31 - (item / 28);              // heavy rows first
    const int seg = item % 28;

    int lr, b, s;
    if (seg < 16)      { lr = 0; s = seg >> 2;        b = seg & 3;        }
    else if (seg < 24) { lr = 1; s = (seg - 16) >> 2; b = (seg - 16) & 3; }
    else               { lr = 2; s = 0;               b = seg - 24;       }
    const int rr = 1 << lr;
    const size_t base = (size_t)b * 8192 + (size_t)s * (2048 << lr);
    const size_t pbase = (size_t)b * (8192 >> lr) + (size_t)s * 2048;
    const int segi = (lr == 0) ? (b * 4 + s) : (lr == 1) ? (b * 2 + s) : b;
    const bf16* Vtt = (lr == 0) ? Vtt1 : (lr == 1) ? Vtt2 : Vtt4;
    const u16* Vseg = (const u16*)Vtt + (size_t)segi * 524288;   // [64 tiles][256][32]
    float* Op = (lr == 0) ? O1 : (lr == 1) ? O2 : O4;
    float* Dp = (lr == 0) ? D1 : (lr == 1) ? D2 : D4;

    const int tid = threadIdx.x, wv = tid >> 6, lane = tid & 63;
    const int l15 = lane & 15, quad = lane >> 4;

    // Q B-fragments (n = q = l15, k = quad*8 + j)
    const int qi = qt * 64 + wv * 16 + l15;
    const bf16* qp = Qb + (base + (size_t)qi * rr) * 256 + quad * 8;
    bf16x8 qf[8];
    #pragma unroll
    for (int ks = 0; ks < 8; ks++) qf[ks] = *(const bf16x8*)(qp + ks * 32);

    f32x4 o[16] = {};
    float m_run = -1e30f, l_run = 0.f;

    // staging maps
    const int krow = tid >> 3, kc = tid & 7;       // K: 32 rows x 8 16B-units
    const u16* Kp = (const u16*)Kb + base * 256;
    const int vrow = tid >> 2, vcol = (tid & 3) * 8;  // V: unit u=tid+256i -> d=u>>2
    u16x8 kpre[4], vpre[4];

    const int nkt = 2 * (qt + 1);                  // >= 2
    {   // prologue: tile 0 -> LDS[0]; tile 1 -> regs
        const u16* kp = Kp + (size_t)krow * rr * 256;
        #pragma unroll
        for (int i = 0; i < 4; i++) kpre[i] = *(const u16x8*)(kp + (kc + 8 * i) * 8);
        #pragma unroll
        for (int i = 0; i < 4; i++) vpre[i] = *(const u16x8*)(Vseg + (size_t)(tid + 256 * i) * 8);
        #pragma unroll
        for (int i = 0; i < 4; i++)
            *(u16x8*)(K_l[0] + krow * 264 + (kc + 8 * i) * 8) = kpre[i];
        #pragma unroll
        for (int i = 0; i < 4; i++)
            *(u16x8*)(V_l[0] + (vrow + 64 * i) * 40 + vcol) = vpre[i];
        const u16* kp1 = Kp + (size_t)(32 + krow) * rr * 256;
        #pragma unroll
        for (int i = 0; i < 4; i++) kpre[i] = *(const u16x8*)(kp1 + (kc + 8 * i) * 8);
        const u16* vp1 = Vseg + 8192;
        #pragma unroll
        for (int i = 0; i < 4; i++) vpre[i] = *(const u16x8*)(vp1 + (size_t)(tid + 256 * i) * 8);
        __syncthreads();
    }

    for (int kt = 0; kt < nkt; kt++) {
        const int buf = kt & 1;
        // write tile kt+1 into the other buffer (its readers finished at the
        // barrier ending iter kt-1), then start loading tile kt+2.
        if (kt + 1 < nkt) {
            #pragma unroll
            for (int i = 0; i < 4; i++)
                *(u16x8*)(K_l[buf ^ 1] + krow * 264 + (kc + 8 * i) * 8) = kpre[i];
            #pragma unroll
            for (int i = 0; i < 4; i++)
                *(u16x8*)(V_l[buf ^ 1] + (vrow + 64 * i) * 40 + vcol) = vpre[i];
        }
        if (kt + 2 < nkt) {
            const u16* kp = Kp + (size_t)((kt + 2) * 32 + krow) * rr * 256;
            #pragma unroll
            for (int i = 0; i < 4; i++) kpre[i] = *(const u16x8*)(kp + (kc + 8 * i) * 8);
            const u16* vp = Vseg + (size_t)(kt + 2) * 8192;
            #pragma unroll
            for (int i = 0; i < 4; i++) vpre[i] = *(const u16x8*)(vp + (size_t)(tid + 256 * i) * 8);
        }

        // S^T = K Q^T : A = K rows (m=key), B = Q (n=q)
        f32x4 sf[2] = {};
        #pragma unroll
        for (int ks = 0; ks < 8; ks++) {
            #pragma unroll
            for (int kb = 0; kb < 2; kb++) {
                bf16x8 kf = *(const bf16x8*)((const bf16*)K_l[buf] + (kb * 16 + l15) * 264 + ks * 32 + quad * 8);
                sf[kb] = MFMA16(kf, qf[ks], sf[kb]);
            }
        }
        // causal mask (diagonal tiles only); running max
        float mx = -1e30f;
        #pragma unroll
        for (int kb = 0; kb < 2; kb++)
            #pragma unroll
            for (int r = 0; r < 4; r++) {
                float v = sf[kb][r];
                if (kt >= 2 * qt) {
                    int key = kt * 32 + kb * 16 + quad * 4 + r;
                    if (key > qi) v = -1e30f;
                }
                sf[kb][r] = v;
                mx = fmaxf(mx, v);
            }
        mx = fmaxf(mx, __shfl_xor(mx, 16));
        mx = fmaxf(mx, __shfl_xor(mx, 32));
        float mold = m_run;
        float mnew = fmaxf(mold, mx);
        m_run = mnew;
        float a = exp2f(mold - mnew);
        float rs = 0.f;
        #pragma unroll
        for (int kb = 0; kb < 2; kb++)
            #pragma unroll
            for (int r = 0; r < 4; r++) {
                float e = exp2f(sf[kb][r] - mnew);
                sf[kb][r] = e;
                rs += e;
            }
        rs += __shfl_xor(rs, 16);
        rs += __shfl_xor(rs, 32);
        l_run = l_run * a + rs;
        if (__any(mnew > mold)) {
            #pragma unroll
            for (int f = 0; f < 16; f++)
                #pragma unroll
                for (int r = 0; r < 4; r++) o[f][r] *= a;
        }
        // P^T B-fragment: pack bf16 pairs, 8 u32 cross-quad shuffles
        unsigned pk00 = pack2(sf[0][0], sf[0][1]);
        unsigned pk01 = pack2(sf[0][2], sf[0][3]);
        unsigned pk10 = pack2(sf[1][0], sf[1][1]);
        unsigned pk11 = pack2(sf[1][2], sf[1][3]);
        int src0 = l15 + 32 * (quad & 1);
        int src1 = src0 + 16;
        unsigned b00 = (unsigned)__shfl((int)pk00, src0, 64);
        unsigned b01 = (unsigned)__shfl((int)pk01, src0, 64);
        unsigned b02 = (unsigned)__shfl((int)pk00, src1, 64);
        unsigned b03 = (unsigned)__shfl((int)pk01, src1, 64);
        unsigned b10 = (unsigned)__shfl((int)pk10, src0, 64);
        unsigned b11 = (unsigned)__shfl((int)pk11, src0, 64);
        unsigned b12 = (unsigned)__shfl((int)pk10, src1, 64);
        unsigned b13 = (unsigned)__shfl((int)pk11, src1, 64);
        bool hi = (quad >> 1) != 0;
        union { bf16x8 v; unsigned u[4]; } pbu;
        pbu.u[0] = hi ? b10 : b00;
        pbu.u[1] = hi ? b11 : b01;
        pbu.u[2] = hi ? b12 : b02;
        pbu.u[3] = hi ? b13 : b03;
        // O^T += V^T P^T : A = V^T rows (m=d) from LDS
        #pragma unroll
        for (int f = 0; f < 16; f++) {
            bf16x8 vf = *(const bf16x8*)((const bf16*)V_l[buf] + (f * 16 + l15) * 40 + quad * 8);
            o[f] = MFMA16(vf, pbu.v, o[f]);
        }
        __syncthreads();
    }

    // epilogue: collision-free store of normalized partial + denom
    float invl = 1.0f / l_run;
    size_t pos = pbase + (size_t)qi;
    if (quad == 0) Dp[pos] = l_run * exp2f(m_run);
    float* orow = Op + pos * 256 + quad * 4;
    #pragma unroll
    for (int f = 0; f < 16; f++) {
        f32x4 v;
        #pragma unroll
        for (int r = 0; r < 4; r++) v[r] = o[f][r] * invl;
        *(f32x4*)(orow + f * 16) = v;
    }
}

// ---------------------------------------------------------------- finalize
// out = (O1*d1 + O2*d2 + O4*d4) / (d1+d2+d4); O1 lives in d_out already.
__global__ void finalize(float* __restrict__ out, const float* __restrict__ O2,
                         const float* __restrict__ O4,
                         const float* __restrict__ D1, const float* __restrict__ D2,
                         const float* __restrict__ D4) {
    int g = blockIdx.x * 256 + threadIdx.x;     // 32768 tokens * 64 chunks
    int t = g >> 6, dc = (g & 63) * 4;
    int b = t >> 13, n = t & 8191;
    float d1 = D1[t];
    float4 o1 = *(float4*)(out + (size_t)t * 256 + dc);
    float ax = o1.x * d1, ay = o1.y * d1, az = o1.z * d1, aw = o1.w * d1;
    float den = d1;
    if ((n & 1) == 0) {
        int pos2 = b * 4096 + (n >> 12) * 2048 + ((n & 4095) >> 1);
        float d2 = D2[pos2];
        const float4 o2 = *(const float4*)(O2 + (size_t)pos2 * 256 + dc);
        ax += o2.x * d2; ay += o2.y * d2; az += o2.z * d2; aw += o2.w * d2;
        den += d2;
    }
    if ((n & 3) == 0) {
        int pos4 = b * 2048 + (n >> 2);
        float d4 = D4[pos4];
        const float4 o4 = *(const float4*)(O4 + (size_t)pos4 * 256 + dc);
        ax += o4.x * d4; ay += o4.y * d4; az += o4.z * d4; aw += o4.w * d4;
        den += d4;
    }
    float inv = 1.0f / den;
    float4 r; r.x = ax * inv; r.y = ay * inv; r.z = az * inv; r.w = aw * inv;
    *(float4*)(out + (size_t)t * 256 + dc) = r;
}

// ---------------------------------------------------------------- launch
extern "C" void kernel_launch(void* const* d_in, const int* in_sizes, int n_in,
                              void* d_out, int out_size, void* d_ws, size_t ws_size,
                              hipStream_t stream) {
    const float* x  = (const float*)d_in[0];
    const float* Wq = (const float*)d_in[1];
    const float* Wk = (const float*)d_in[2];
    const float* Wv = (const float*)d_in[3];
    float* out = (float*)d_out;

    char* ws = (char*)d_ws;
    bf16* Qb   = (bf16*)(ws);                        // 16 MB
    bf16* Kb   = (bf16*)(ws + 16777216);             // 16 MB
    bf16* Vtt1 = (bf16*)(ws + 33554432);             // 16 MB  [16 seg][64 kt][256][32]
    bf16* Vtt2 = (bf16*)(ws + 50331648);             //  8 MB
    bf16* Vtt4 = (bf16*)(ws + 58720256);             //  4 MB
    bf16* Wbt  = (bf16*)(ws + 62914560);             // 384 KB
    float* O2  = (float*)(ws + 63307776);            // 16 MB
    float* O4  = (float*)(ws + 80084992);            //  8 MB
    float* D1  = (float*)(ws + 88473600);            // 128 KB
    float* D2  = (float*)(ws + 88604672);            //  64 KB
    float* D4  = (float*)(ws + 88670208);            //  32 KB

    cvt_w<<<768, 256, 0, stream>>>(Wq, Wk, Wv, Wbt);
    qkv_gemm<<<dim3(512, 3), 256, 0, stream>>>(x, Wbt, Qb, Kb, Vtt1, Vtt2, Vtt4);
    attn<<<896, 256, 0, stream>>>(Qb, Kb, Vtt1, Vtt2, Vtt4, out, O2, O4, D1, D2, D4);
    finalize<<<8192, 256, 0, stream>>>(out, O2, O4, D1, D2, D4);
}